// Round 2
// baseline (607.542 us; speedup 1.0000x reference)
//
#include <hip/hip_runtime.h>

#define EPS 1e-12f

// problem sizes
#define BATCH 4
#define CIN   768
#define LIN   4096
#define DCODE 128
#define TOUT  2048
#define NROWS (BATCH*TOUT)   // 8192
#define KCB   8192

// ws layout (bytes)
#define OFF_WT   0u          // 2304*128 f32 = 1,179,648
#define OFF_CBN  1179648u    // 8192*128 f32 = 4,194,304
#define OFF_CN2  5373952u    // 8192 f32
#define OFF_BS   5406720u    // 4*8192 f32
#define OFF_BI   5537792u    // 4*8192 i32
#define OFF_PART 5668864u    // 2*8192*128 f32 (part0 reused as enc)

// ---------------------------------------------------------------------------
// Transpose conv weights: w[n][c][j] -> wt[(c*3+j)*128 + n]
__global__ __launch_bounds__(256) void k_wt(const float* __restrict__ w,
                                            float* __restrict__ wt) {
    int i = blockIdx.x * 256 + threadIdx.x;
    if (i < 2304 * 128) {
        int n  = i & 127;
        int cj = i >> 7;
        wt[i] = w[n * 2304 + cj];
    }
}

// ---------------------------------------------------------------------------
// Normalize codebook rows; cn2[k] = ||c_norm||^2. One wave per codeword.
__global__ __launch_bounds__(256) void k_cbnorm(const float* __restrict__ cb,
                                                float* __restrict__ cbn,
                                                float* __restrict__ cn2) {
    int wid  = threadIdx.x >> 6;
    int lane = threadIdx.x & 63;
    int k = blockIdx.x * 4 + wid;
    const float2* src = (const float2*)cb + (size_t)k * 64;
    float2* dst = (float2*)cbn + (size_t)k * 64;
    float2 v = src[lane];
    float ss = v.x * v.x + v.y * v.y;
    #pragma unroll
    for (int m = 1; m < 64; m <<= 1) ss += __shfl_xor(ss, m);
    float inv = 1.0f / fmaxf(sqrtf(ss), EPS);
    dst[lane] = make_float2(v.x * inv, v.y * inv);
    if (lane == 0) cn2[k] = ss * inv * inv;
}

// ---------------------------------------------------------------------------
// Conv1d (stride 2, pad 1, k=3), K split in 2 halves across blockIdx.z.
// Block: 256 thr = 8 tt-groups(x4 t) x 32 tn-groups(x4 n). 32 t-positions/block.
__global__ __launch_bounds__(256) void k_conv(const float* __restrict__ x,
                                              const float* __restrict__ wt,
                                              float* __restrict__ part) {
    __shared__ float xs[8 * 66];
    __shared__ float wsh[24 * 128];
    const int tn = threadIdx.x & 31;
    const int tt = threadIdx.x >> 5;
    const int t0 = blockIdx.x * 32;
    const int b  = blockIdx.y;
    const int ks = blockIdx.z;
    const int c_base = ks * 384;

    float4 acc[4];
    #pragma unroll
    for (int i = 0; i < 4; ++i) acc[i] = make_float4(0.f, 0.f, 0.f, 0.f);

    for (int cc = 0; cc < 384; cc += 8) {
        __syncthreads();
        // stage x: 8 channel-rows x 65 samples (sample s -> input idx 2*t0-1+s)
        {
            const float* xg = x + ((size_t)(b * CIN + c_base + cc + tt)) * LIN;
            int base = 2 * t0 - 1;
            for (int s = tn; s < 65; s += 32) {
                int g = base + s;
                xs[tt * 66 + s] = (g >= 0 && g < LIN) ? xg[g] : 0.f;
            }
        }
        // stage w: 8 ch x 3 taps x 128 n, coalesced from wt
        {
            const float* wg = wt + (size_t)(c_base + cc) * 384;
            for (int i = threadIdx.x; i < 3072; i += 256) wsh[i] = wg[i];
        }
        __syncthreads();
        #pragma unroll
        for (int c8 = 0; c8 < 8; ++c8) {
            float4 wv[3];
            #pragma unroll
            for (int j = 0; j < 3; ++j)
                wv[j] = ((const float4*)wsh)[(c8 * 3 + j) * 32 + tn];
            float xr[9];
            const float* xb = xs + c8 * 66 + tt * 8;
            #pragma unroll
            for (int u = 0; u < 4; ++u) {
                float2 p = ((const float2*)xb)[u];
                xr[2 * u] = p.x; xr[2 * u + 1] = p.y;
            }
            xr[8] = xb[8];
            #pragma unroll
            for (int i = 0; i < 4; ++i) {
                #pragma unroll
                for (int j = 0; j < 3; ++j) {
                    float xv = xr[2 * i + j];
                    acc[i].x = fmaf(xv, wv[j].x, acc[i].x);
                    acc[i].y = fmaf(xv, wv[j].y, acc[i].y);
                    acc[i].z = fmaf(xv, wv[j].z, acc[i].z);
                    acc[i].w = fmaf(xv, wv[j].w, acc[i].w);
                }
            }
        }
    }
    // write partial sums
    float4* pb = (float4*)(part + ((size_t)ks * NROWS + (size_t)b * TOUT + t0) * DCODE);
    #pragma unroll
    for (int i = 0; i < 4; ++i) {
        int t_loc = tt * 4 + i;
        pb[t_loc * 32 + tn] = acc[i];
    }
}

// ---------------------------------------------------------------------------
// Combine K-halves + L2-normalize encodings in place (enc = part0 region).
__global__ __launch_bounds__(256) void k_encnorm(float* __restrict__ part) {
    int wid  = threadIdx.x >> 6;
    int lane = threadIdx.x & 63;
    int r = blockIdx.x * 4 + wid;
    float2* p0 = (float2*)part + (size_t)r * 64;
    const float2* p1 = (const float2*)(part + (size_t)NROWS * DCODE) + (size_t)r * 64;
    float2 a = p0[lane];
    float2 c = p1[lane];
    a.x += c.x; a.y += c.y;
    float ss = a.x * a.x + a.y * a.y;
    #pragma unroll
    for (int m = 1; m < 64; m <<= 1) ss += __shfl_xor(ss, m);
    float inv = 1.0f / fmaxf(sqrtf(ss), EPS);
    p0[lane] = make_float2(a.x * inv, a.y * inv);
}

// ---------------------------------------------------------------------------
// Scores + argmax. Block: 64 rows x 2048 codewords (quarter), 256 thr,
// 4x4 register tile, XOR-swizzled LDS tiles (row>>3 into float4 index).
__global__ __launch_bounds__(256) void k_dist(const float* __restrict__ enc,
                                              const float* __restrict__ cbn,
                                              const float* __restrict__ cn2,
                                              float* __restrict__ best_s,
                                              int* __restrict__ best_i) {
    extern __shared__ float4 sm[];
    float4* encS = sm;         // 64 rows x 32 float4
    float4* cbS  = sm + 2048;  // 64 rows x 32 float4
    const int tid = threadIdx.x;
    const int tc = tid & 15;
    const int tr = tid >> 4;
    const int r0 = blockIdx.x * 64;
    const int kq = blockIdx.y;
    const float4* enc4 = (const float4*)enc;
    const float4* cb4  = (const float4*)cbn;

    for (int i = tid; i < 2048; i += 256) {
        int r = i >> 5, d4 = i & 31;
        encS[(r << 5) | (d4 ^ (r >> 3))] = enc4[(size_t)r0 * 32 + i];
    }

    float bs[4]; int bi[4];
    #pragma unroll
    for (int i = 0; i < 4; ++i) { bs[i] = -3.4e38f; bi[i] = 0; }

    const int rsA = tr >> 1;  // (4*tr+i)>>3 is constant over i=0..3
    const int rsB = tc >> 1;

    for (int k0 = kq * 2048; k0 < kq * 2048 + 2048; k0 += 64) {
        __syncthreads();
        for (int i = tid; i < 2048; i += 256) {
            int r = i >> 5, d4 = i & 31;
            cbS[(r << 5) | (d4 ^ (r >> 3))] = cb4[(size_t)k0 * 32 + i];
        }
        __syncthreads();

        float4 acc[4][4];
        #pragma unroll
        for (int i = 0; i < 4; ++i)
            #pragma unroll
            for (int j = 0; j < 4; ++j) acc[i][j] = make_float4(0.f, 0.f, 0.f, 0.f);

        #pragma unroll 4
        for (int d4 = 0; d4 < 32; ++d4) {
            int dA = d4 ^ rsA, dB = d4 ^ rsB;
            float4 a[4], bb[4];
            #pragma unroll
            for (int i = 0; i < 4; ++i) a[i]  = encS[((tr * 4 + i) << 5) | dA];
            #pragma unroll
            for (int j = 0; j < 4; ++j) bb[j] = cbS[((tc * 4 + j) << 5) | dB];
            #pragma unroll
            for (int i = 0; i < 4; ++i) {
                #pragma unroll
                for (int j = 0; j < 4; ++j) {
                    acc[i][j].x = fmaf(a[i].x, bb[j].x, acc[i][j].x);
                    acc[i][j].y = fmaf(a[i].y, bb[j].y, acc[i][j].y);
                    acc[i][j].z = fmaf(a[i].z, bb[j].z, acc[i][j].z);
                    acc[i][j].w = fmaf(a[i].w, bb[j].w, acc[i][j].w);
                }
            }
        }
        #pragma unroll
        for (int i = 0; i < 4; ++i) {
            #pragma unroll
            for (int j = 0; j < 4; ++j) {
                float dot = (acc[i][j].x + acc[i][j].y) + (acc[i][j].z + acc[i][j].w);
                int k = k0 + tc * 4 + j;
                float sc = 2.0f * dot - cn2[k];
                if (sc > bs[i]) { bs[i] = sc; bi[i] = k; }  // strict > => lowest idx
            }
        }
    }
    // reduce across the 16 tc lanes (within-wave groups)
    #pragma unroll
    for (int i = 0; i < 4; ++i) {
        #pragma unroll
        for (int m = 1; m < 16; m <<= 1) {
            float os = __shfl_xor(bs[i], m);
            int   oi = __shfl_xor(bi[i], m);
            if (os > bs[i] || (os == bs[i] && oi < bi[i])) { bs[i] = os; bi[i] = oi; }
        }
        if (tc == 0) {
            int r = r0 + tr * 4 + i;
            best_s[(size_t)kq * NROWS + r] = bs[i];
            best_i[(size_t)kq * NROWS + r] = bi[i];
        }
    }
}

// ---------------------------------------------------------------------------
// Merge the 4 codeword-quarters per row; output index as INT32 (harness reads
// d_out as int32 for integer-dtype references — round-1 fix).
__global__ __launch_bounds__(256) void k_merge(const float* __restrict__ bs,
                                               const int* __restrict__ bi,
                                               int* __restrict__ out) {
    int r = blockIdx.x * 256 + threadIdx.x;
    if (r >= NROWS) return;
    float s = bs[r]; int i = bi[r];
    #pragma unroll
    for (int q = 1; q < 4; ++q) {
        float s2 = bs[(size_t)q * NROWS + r];
        int   i2 = bi[(size_t)q * NROWS + r];
        if (s2 > s || (s2 == s && i2 < i)) { s = s2; i = i2; }
    }
    out[r] = i;
}

// ---------------------------------------------------------------------------
extern "C" void kernel_launch(void* const* d_in, const int* in_sizes, int n_in,
                              void* d_out, int out_size, void* d_ws, size_t ws_size,
                              hipStream_t stream) {
    const float* x  = (const float*)d_in[0];  // [4][768][4096]
    const float* w  = (const float*)d_in[1];  // [128][768][3]
    const float* cb = (const float*)d_in[2];  // [8192][128]
    char* ws = (char*)d_ws;
    float* wt   = (float*)(ws + OFF_WT);
    float* cbn  = (float*)(ws + OFF_CBN);
    float* cn2  = (float*)(ws + OFF_CN2);
    float* bs   = (float*)(ws + OFF_BS);
    int*   bi   = (int*)(ws + OFF_BI);
    float* part = (float*)(ws + OFF_PART);
    int*   out  = (int*)d_out;

    k_wt     <<<1152, 256, 0, stream>>>(w, wt);
    k_cbnorm <<<2048, 256, 0, stream>>>(cb, cbn, cn2);
    k_conv   <<<dim3(64, 4, 2), 256, 0, stream>>>(x, wt, part);
    k_encnorm<<<2048, 256, 0, stream>>>(part);
    k_dist   <<<dim3(128, 4), 256, 65536, stream>>>(part, cbn, cn2, bs, bi);
    k_merge  <<<32, 256, 0, stream>>>(bs, bi, out);
}

// Round 4
// 370.382 us; speedup vs baseline: 1.6403x; 1.6403x over previous
//
#include <hip/hip_runtime.h>

#define EPS 1e-12f

// problem sizes
#define BATCH 4
#define CIN   768
#define LIN   4096
#define DCODE 128
#define TOUT  2048
#define NROWS (BATCH*TOUT)   // 8192
#define KCB   8192

// ws layout (bytes)
#define OFF_WT   0u          // 2304*128 f32           = 1,179,648
#define OFF_CN2  1179648u    // 8192 f32               = 32,768
#define OFF_BS   1212416u    // 4*8192 f32             = 131,072
#define OFF_BI   1343488u    // 4*8192 i32             = 131,072
#define OFF_EH   1474560u    // 8192*128 f16           = 2,097,152
#define OFF_EL   3571712u    // 8192*128 f16           = 2,097,152
#define OFF_CH   5668864u    // 8192*128 f16           = 2,097,152
#define OFF_CL   7766016u    // 8192*128 f16           = 2,097,152
#define OFF_PART 9863168u    // 2*8192*128 f32         = 8,388,608  (end ~18.3MB)

typedef _Float16 half_t;
typedef __attribute__((ext_vector_type(8))) _Float16 half8;
typedef __attribute__((ext_vector_type(2))) _Float16 half2v;
typedef __attribute__((ext_vector_type(4))) float f32x4;

// ---------------------------------------------------------------------------
// Transpose conv weights: w[n][c][j] -> wt[(c*3+j)*128 + n]
__global__ __launch_bounds__(256) void k_wt(const float* __restrict__ w,
                                            float* __restrict__ wt) {
    int i = blockIdx.x * 256 + threadIdx.x;
    if (i < 2304 * 128) {
        int n  = i & 127;
        int cj = i >> 7;
        wt[i] = w[n * 2304 + cj];
    }
}

// ---------------------------------------------------------------------------
// Normalize codebook rows -> fp16 hi/lo split; cn2[k] = ||c_norm||^2.
__global__ __launch_bounds__(256) void k_cbnorm(const float* __restrict__ cb,
                                                half_t* __restrict__ ch,
                                                half_t* __restrict__ cl,
                                                float* __restrict__ cn2) {
    int wid  = threadIdx.x >> 6;
    int lane = threadIdx.x & 63;
    int k = blockIdx.x * 4 + wid;
    const float2* src = (const float2*)cb + (size_t)k * 64;
    float2 v = src[lane];
    float ss = v.x * v.x + v.y * v.y;
    #pragma unroll
    for (int m = 1; m < 64; m <<= 1) ss += __shfl_xor(ss, m);
    float inv = 1.0f / fmaxf(sqrtf(ss), EPS);
    float nx = v.x * inv, ny = v.y * inv;
    half_t hx = (half_t)nx, hy = (half_t)ny;
    half_t lx = (half_t)(nx - (float)hx), ly = (half_t)(ny - (float)hy);
    ((half2v*)ch)[(size_t)k * 64 + lane] = half2v{hx, hy};
    ((half2v*)cl)[(size_t)k * 64 + lane] = half2v{lx, ly};
    if (lane == 0) cn2[k] = ss * inv * inv;
}

// ---------------------------------------------------------------------------
// Conv1d (stride 2, pad 1, k=3), K split in 2 halves across blockIdx.z.
__global__ __launch_bounds__(256) void k_conv(const float* __restrict__ x,
                                              const float* __restrict__ wt,
                                              float* __restrict__ part) {
    __shared__ float xs[8 * 66];
    __shared__ float wsh[24 * 128];
    const int tn = threadIdx.x & 31;
    const int tt = threadIdx.x >> 5;
    const int t0 = blockIdx.x * 32;
    const int b  = blockIdx.y;
    const int ks = blockIdx.z;
    const int c_base = ks * 384;

    float4 acc[4];
    #pragma unroll
    for (int i = 0; i < 4; ++i) acc[i] = make_float4(0.f, 0.f, 0.f, 0.f);

    for (int cc = 0; cc < 384; cc += 8) {
        __syncthreads();
        {
            const float* xg = x + ((size_t)(b * CIN + c_base + cc + tt)) * LIN;
            int base = 2 * t0 - 1;
            for (int s = tn; s < 65; s += 32) {
                int g = base + s;
                xs[tt * 66 + s] = (g >= 0 && g < LIN) ? xg[g] : 0.f;
            }
        }
        {
            const float* wg = wt + (size_t)(c_base + cc) * 384;
            for (int i = threadIdx.x; i < 3072; i += 256) wsh[i] = wg[i];
        }
        __syncthreads();
        #pragma unroll
        for (int c8 = 0; c8 < 8; ++c8) {
            float4 wv[3];
            #pragma unroll
            for (int j = 0; j < 3; ++j)
                wv[j] = ((const float4*)wsh)[(c8 * 3 + j) * 32 + tn];
            float xr[9];
            const float* xb = xs + c8 * 66 + tt * 8;
            #pragma unroll
            for (int u = 0; u < 4; ++u) {
                float2 p = ((const float2*)xb)[u];
                xr[2 * u] = p.x; xr[2 * u + 1] = p.y;
            }
            xr[8] = xb[8];
            #pragma unroll
            for (int i = 0; i < 4; ++i) {
                #pragma unroll
                for (int j = 0; j < 3; ++j) {
                    float xv = xr[2 * i + j];
                    acc[i].x = fmaf(xv, wv[j].x, acc[i].x);
                    acc[i].y = fmaf(xv, wv[j].y, acc[i].y);
                    acc[i].z = fmaf(xv, wv[j].z, acc[i].z);
                    acc[i].w = fmaf(xv, wv[j].w, acc[i].w);
                }
            }
        }
    }
    float4* pb = (float4*)(part + ((size_t)ks * NROWS + (size_t)b * TOUT + t0) * DCODE);
    #pragma unroll
    for (int i = 0; i < 4; ++i) {
        int t_loc = tt * 4 + i;
        pb[t_loc * 32 + tn] = acc[i];
    }
}

// ---------------------------------------------------------------------------
// Combine K-halves + L2-normalize encodings -> fp16 hi/lo split.
__global__ __launch_bounds__(256) void k_encnorm(const float* __restrict__ part,
                                                 half_t* __restrict__ eh,
                                                 half_t* __restrict__ el) {
    int wid  = threadIdx.x >> 6;
    int lane = threadIdx.x & 63;
    int r = blockIdx.x * 4 + wid;
    const float2* p0 = (const float2*)part + (size_t)r * 64;
    const float2* p1 = (const float2*)(part + (size_t)NROWS * DCODE) + (size_t)r * 64;
    float2 a = p0[lane];
    float2 c = p1[lane];
    a.x += c.x; a.y += c.y;
    float ss = a.x * a.x + a.y * a.y;
    #pragma unroll
    for (int m = 1; m < 64; m <<= 1) ss += __shfl_xor(ss, m);
    float inv = 1.0f / fmaxf(sqrtf(ss), EPS);
    float nx = a.x * inv, ny = a.y * inv;
    half_t hx = (half_t)nx, hy = (half_t)ny;
    half_t lx = (half_t)(nx - (float)hx), ly = (half_t)(ny - (float)hy);
    ((half2v*)eh)[(size_t)r * 64 + lane] = half2v{hx, hy};
    ((half2v*)el)[(size_t)r * 64 + lane] = half2v{lx, ly};
}

// ---------------------------------------------------------------------------
// MFMA dist+argmax. Block = 4 waves x 32 rows = 128 rows; blockIdx.y = col
// quarter (2048 codewords). fp16 hi/lo split: dot = hh + hl + lh (fp32-class).
// B tiles (128 cols x 128 k, hi+lo = 64KB) double-buffered in LDS, staged via
// global_load_lds w=16 with PRE-SWIZZLED global source (linear LDS dest);
// reads use XOR swizzle kbyte ^= (col&7)<<4 -> conflict-free ds_read_b128.
__global__ __launch_bounds__(256, 1) void k_dist(const half_t* __restrict__ eh,
                                                 const half_t* __restrict__ el,
                                                 const half_t* __restrict__ ch,
                                                 const half_t* __restrict__ cl,
                                                 const float* __restrict__ cn2,
                                                 float* __restrict__ best_s,
                                                 int* __restrict__ best_i) {
    extern __shared__ char smem[];          // 2 x (32KB hi + 32KB lo)
    const int tid  = threadIdx.x;
    const int lane = tid & 63;
    const int w    = tid >> 6;              // wave 0..3
    const int lr   = lane & 15;
    const int lg   = lane >> 4;
    const int r0   = blockIdx.x * 128;
    const int kqbase = blockIdx.y * 2048;

    // A fragments in registers: rows r0 + w*32 + g*16 + lr, k = kc*32 + lg*8
    half8 ah[2][4], al[2][4];
    #pragma unroll
    for (int g = 0; g < 2; ++g) {
        int row = r0 + w * 32 + g * 16 + lr;
        const half8* ph = (const half8*)(eh + (size_t)row * 128 + lg * 8);
        const half8* pl = (const half8*)(el + (size_t)row * 128 + lg * 8);
        #pragma unroll
        for (int kc = 0; kc < 4; ++kc) { ah[g][kc] = ph[kc * 4]; al[g][kc] = pl[kc * 4]; }
    }

    // stage tile t into LDS buffer `buf`: wave w covers mat=w>>1 (hi/lo),
    // col-half=w&1. Each instruction: 4 consecutive cols x 256B = 1KB contig.
    const half_t* msrc = (w >> 1) ? cl : ch;
    auto stage = [&](int t, int buf) {
        #pragma unroll
        for (int i = 0; i < 16; ++i) {
            int col_l = (w & 1) * 64 + i * 4 + lg;                 // tile-local col
            int ksrc  = (lr * 16) ^ ((col_l & 7) << 4);            // inverse swizzle
            const char* g = (const char*)msrc
                          + ((size_t)(kqbase + t * 128 + col_l)) * 256 + ksrc;
            char* l = smem + buf * 65536 + w * 16384 + i * 1024;   // + lane*16 by HW
            __builtin_amdgcn_global_load_lds(
                (const __attribute__((address_space(1))) void*)(uintptr_t)g,
                (__attribute__((address_space(3))) void*)(uintptr_t)l, 16, 0, 0);
        }
    };

    float bs[2][4]; int bi[2][4];
    #pragma unroll
    for (int g = 0; g < 2; ++g)
        #pragma unroll
        for (int r = 0; r < 4; ++r) { bs[g][r] = -3.4e38f; bi[g][r] = 0; }

    stage(0, 0);
    __syncthreads();   // drains vmcnt -> tile 0 ready

    int buf = 0;
    for (int t = 0; t < 16; ++t) {
        if (t < 15) stage(t + 1, buf ^ 1);
        float cnv[8];
        #pragma unroll
        for (int cg = 0; cg < 8; ++cg)
            cnv[cg] = cn2[kqbase + t * 128 + cg * 16 + lr];
        const char* bhp = smem + buf * 65536;
        const char* blp = bhp + 32768;
        #pragma unroll 2
        for (int cg = 0; cg < 8; ++cg) {
            int col   = cg * 16 + lr;
            int kswz  = (col & 7) << 4;
            int cbyte = col * 256;
            half8 bhf[4], blf[4];
            #pragma unroll
            for (int kc = 0; kc < 4; ++kc) {
                int kb = (kc * 64 + lg * 16) ^ kswz;
                bhf[kc] = *(const half8*)(bhp + cbyte + kb);
                blf[kc] = *(const half8*)(blp + cbyte + kb);
            }
            f32x4 acc[2] = {f32x4{0.f,0.f,0.f,0.f}, f32x4{0.f,0.f,0.f,0.f}};
            #pragma unroll
            for (int kc = 0; kc < 4; ++kc) {
                #pragma unroll
                for (int g = 0; g < 2; ++g) {
                    acc[g] = __builtin_amdgcn_mfma_f32_16x16x32_f16(ah[g][kc], bhf[kc], acc[g], 0, 0, 0);
                    acc[g] = __builtin_amdgcn_mfma_f32_16x16x32_f16(al[g][kc], bhf[kc], acc[g], 0, 0, 0);
                    acc[g] = __builtin_amdgcn_mfma_f32_16x16x32_f16(ah[g][kc], blf[kc], acc[g], 0, 0, 0);
                }
            }
            int n = kqbase + t * 128 + cg * 16 + lr;
            #pragma unroll
            for (int g = 0; g < 2; ++g)
                #pragma unroll
                for (int r = 0; r < 4; ++r) {
                    float sc = 2.0f * acc[g][r] - cnv[cg];
                    if (sc > bs[g][r]) { bs[g][r] = sc; bi[g][r] = n; }
                }
        }
        __syncthreads();
        buf ^= 1;
    }

    // reduce over the 16 cols held across lanes with the same lg
    #pragma unroll
    for (int g = 0; g < 2; ++g)
        #pragma unroll
        for (int r = 0; r < 4; ++r) {
            float s = bs[g][r]; int i = bi[g][r];
            #pragma unroll
            for (int m = 1; m < 16; m <<= 1) {
                float os = __shfl_xor(s, m);
                int   oi = __shfl_xor(i, m);
                if (os > s || (os == s && oi < i)) { s = os; i = oi; }
            }
            if (lr == 0) {
                int row = r0 + w * 32 + g * 16 + lg * 4 + r;
                best_s[(size_t)blockIdx.y * NROWS + row] = s;
                best_i[(size_t)blockIdx.y * NROWS + row] = i;
            }
        }
}

// ---------------------------------------------------------------------------
__global__ __launch_bounds__(256) void k_merge(const float* __restrict__ bs,
                                               const int* __restrict__ bi,
                                               int* __restrict__ out) {
    int r = blockIdx.x * 256 + threadIdx.x;
    if (r >= NROWS) return;
    float s = bs[r]; int i = bi[r];
    #pragma unroll
    for (int q = 1; q < 4; ++q) {
        float s2 = bs[(size_t)q * NROWS + r];
        int   i2 = bi[(size_t)q * NROWS + r];
        if (s2 > s || (s2 == s && i2 < i)) { s = s2; i = i2; }
    }
    out[r] = i;
}

// ---------------------------------------------------------------------------
extern "C" void kernel_launch(void* const* d_in, const int* in_sizes, int n_in,
                              void* d_out, int out_size, void* d_ws, size_t ws_size,
                              hipStream_t stream) {
    const float* x  = (const float*)d_in[0];
    const float* w  = (const float*)d_in[1];
    const float* cb = (const float*)d_in[2];
    char* ws = (char*)d_ws;
    float*  wt   = (float*)(ws + OFF_WT);
    float*  cn2  = (float*)(ws + OFF_CN2);
    float*  bs   = (float*)(ws + OFF_BS);
    int*    bi   = (int*)(ws + OFF_BI);
    half_t* eh   = (half_t*)(ws + OFF_EH);
    half_t* el   = (half_t*)(ws + OFF_EL);
    half_t* chh  = (half_t*)(ws + OFF_CH);
    half_t* cll  = (half_t*)(ws + OFF_CL);
    float*  part = (float*)(ws + OFF_PART);
    int*    out  = (int*)d_out;

    hipFuncSetAttribute((const void*)k_dist,
                        hipFuncAttributeMaxDynamicSharedMemorySize, 131072);

    k_wt     <<<1152, 256, 0, stream>>>(w, wt);
    k_cbnorm <<<2048, 256, 0, stream>>>(cb, chh, cll, cn2);
    k_conv   <<<dim3(64, 4, 2), 256, 0, stream>>>(x, wt, part);
    k_encnorm<<<2048, 256, 0, stream>>>(part, eh, el);
    k_dist   <<<dim3(64, 4), 256, 131072, stream>>>(eh, el, chh, cll, cn2, bs, bi);
    k_merge  <<<32, 256, 0, stream>>>(bs, bi, out);
}

// Round 5
// 206.936 us; speedup vs baseline: 2.9359x; 1.7898x over previous
//
#include <hip/hip_runtime.h>

#define EPS 1e-12f

// problem sizes
#define BATCH 4
#define CIN   768
#define LIN   4096
#define DCODE 128
#define TOUT  2048
#define NROWS (BATCH*TOUT)   // 8192
#define KCB   8192
#define KCONV 2304           // 3*768, k = j*768 + c (j-major)

// ws layout (bytes) — total ~68.6 MB
#define OFF_CN2  0u          // 8192 f32
#define OFF_BS   32768u      // 4*8192 f32
#define OFF_BI   163840u     // 4*8192 i32
#define OFF_EH   294912u     // 8192*128 f16
#define OFF_EL   2392064u
#define OFF_CH   4489216u
#define OFF_CL   6586368u
#define OFF_WHT  8683520u    // 128*2304 f16 = 589,824
#define OFF_WLT  9273344u
#define OFF_PART 9863168u    // 2*8192*128 f32 = 8,388,608
#define OFF_XTH  18251776u   // 4*4096*768 f16 = 25,165,824
#define OFF_XTL  43417600u   // end 68,583,424

typedef _Float16 half_t;
typedef __attribute__((ext_vector_type(8))) _Float16 half8;
typedef __attribute__((ext_vector_type(2))) _Float16 half2v;
typedef __attribute__((ext_vector_type(4))) float f32x4;

// ---------------------------------------------------------------------------
// Weights -> fp16 hi/lo, layout wT[n][k], k = j*768 + c (matches cbn layout
// so conv B-staging is identical to k_dist's proven stage pattern).
__global__ __launch_bounds__(256) void k_wt2(const float* __restrict__ w,
                                             half_t* __restrict__ wht,
                                             half_t* __restrict__ wlt) {
    int k = blockIdx.x * 256 + threadIdx.x;
    int n = blockIdx.y;
    if (k >= KCONV) return;
    int j = (k >= 1536) ? 2 : (k >= 768) ? 1 : 0;
    int c = k - j * 768;
    float v = w[(size_t)n * KCONV + c * 3 + j];
    half_t h = (half_t)v;
    wht[(size_t)n * KCONV + k] = h;
    wlt[(size_t)n * KCONV + k] = (half_t)(v - (float)h);
}

// ---------------------------------------------------------------------------
// Transpose x[b][c][s] -> xt[b][s][c] as fp16 hi/lo (LDS 32x33 tile).
__global__ __launch_bounds__(256) void k_xt(const float* __restrict__ x,
                                            half_t* __restrict__ xth,
                                            half_t* __restrict__ xtl) {
    __shared__ float tile[32][33];
    const int s0 = blockIdx.x * 32;
    const int c0 = blockIdx.y * 32;
    const int b  = blockIdx.z;
    const int sl = threadIdx.x & 31;
    const int cl = threadIdx.x >> 5;
    const float* xg = x + ((size_t)b * CIN + c0) * LIN + s0;
    #pragma unroll
    for (int p = 0; p < 4; ++p) {
        int c = cl + p * 8;
        tile[c][sl] = xg[(size_t)c * LIN + sl];
    }
    __syncthreads();
    const int wcc = (threadIdx.x & 15) * 2;
    const int wss = threadIdx.x >> 4;
    #pragma unroll
    for (int p = 0; p < 2; ++p) {
        int s = wss + p * 16;
        float v0 = tile[wcc][s], v1 = tile[wcc + 1][s];
        half_t h0 = (half_t)v0, h1 = (half_t)v1;
        half_t l0 = (half_t)(v0 - (float)h0), l1 = (half_t)(v1 - (float)h1);
        size_t o = ((size_t)b * LIN + s0 + s) * CIN + c0 + wcc;
        *(half2v*)(xth + o) = half2v{h0, h1};
        *(half2v*)(xtl + o) = half2v{l0, l1};
    }
}

// ---------------------------------------------------------------------------
// Normalize codebook rows -> fp16 hi/lo split; cn2[k] = ||c_norm||^2.
__global__ __launch_bounds__(256) void k_cbnorm(const float* __restrict__ cb,
                                                half_t* __restrict__ ch,
                                                half_t* __restrict__ cl,
                                                float* __restrict__ cn2) {
    int wid  = threadIdx.x >> 6;
    int lane = threadIdx.x & 63;
    int k = blockIdx.x * 4 + wid;
    const float2* src = (const float2*)cb + (size_t)k * 64;
    float2 v = src[lane];
    float ss = v.x * v.x + v.y * v.y;
    #pragma unroll
    for (int m = 1; m < 64; m <<= 1) ss += __shfl_xor(ss, m);
    float inv = 1.0f / fmaxf(sqrtf(ss), EPS);
    float nx = v.x * inv, ny = v.y * inv;
    half_t hx = (half_t)nx, hy = (half_t)ny;
    half_t lx = (half_t)(nx - (float)hx), ly = (half_t)(ny - (float)hy);
    ((half2v*)ch)[(size_t)k * 64 + lane] = half2v{hx, hy};
    ((half2v*)cl)[(size_t)k * 64 + lane] = half2v{lx, ly};
    if (lane == 0) cn2[k] = ss * inv * inv;
}

// ---------------------------------------------------------------------------
// Conv as MFMA GEMM: part[ks][row=(b,t)][n] = sum_{k in K-half} xt[b][s][c]*wT[n][k],
// s = 2t-1+j (zero-padded), k = j*768+c. 64-row M-tiles x 2 K-halves = 256 blocks.
// 4 waves = 2 row-halves x 2 col-halves. B double-buffered in LDS (64KB chunks),
// staged exactly like k_dist; A-frags predicated-loaded from xt per chunk.
__global__ __launch_bounds__(256, 1) void k_conv_mfma(
        const half_t* __restrict__ xth, const half_t* __restrict__ xtl,
        const half_t* __restrict__ wht, const half_t* __restrict__ wlt,
        float* __restrict__ part) {
    extern __shared__ char smem[];   // 2 x (32KB hi + 32KB lo)
    const int tid  = threadIdx.x;
    const int lane = tid & 63;
    const int w    = tid >> 6;
    const int wr   = w >> 1;
    const int wc   = w & 1;
    const int lr   = lane & 15;
    const int lg   = lane >> 4;
    const int r0   = blockIdx.x * 64;
    const int ks   = blockIdx.y;
    const int b    = r0 >> 11;
    const int t00  = r0 & 2047;
    const int kbase = ks * 1152;

    const half_t* msrc = (w >> 1) ? wlt : wht;
    auto stage = [&](int t, int buf) {
        int k0 = kbase + t * 128;
        #pragma unroll
        for (int i = 0; i < 16; ++i) {
            int col_l = (w & 1) * 64 + i * 4 + lg;
            int ksrc  = (lr * 16) ^ ((col_l & 7) << 4);   // inverse swizzle
            const char* g = (const char*)msrc + (size_t)col_l * 4608
                          + (size_t)k0 * 2 + ksrc;
            char* l = smem + buf * 65536 + w * 16384 + i * 1024;  // +lane*16 HW
            __builtin_amdgcn_global_load_lds(
                (const __attribute__((address_space(1))) void*)(uintptr_t)g,
                (__attribute__((address_space(3))) void*)(uintptr_t)l, 16, 0, 0);
        }
    };

    f32x4 acc[2][4];
    #pragma unroll
    for (int g = 0; g < 2; ++g)
        #pragma unroll
        for (int cg = 0; cg < 4; ++cg) acc[g][cg] = f32x4{0.f, 0.f, 0.f, 0.f};

    stage(0, 0);
    __syncthreads();

    int buf = 0;
    for (int t = 0; t < 9; ++t) {
        int k0 = kbase + t * 128;
        int j  = (k0 >= 1536) ? 2 : (k0 >= 768) ? 1 : 0;
        int c0 = k0 - j * 768;
        // A fragments for this chunk (rows stride-2 in s; edge rows zeroed)
        half8 ah[2][4], al[2][4];
        #pragma unroll
        for (int g = 0; g < 2; ++g) {
            int trow = t00 + wr * 32 + g * 16 + lr;
            int s = 2 * trow - 1 + j;
            bool valid = (unsigned)s < (unsigned)LIN;
            size_t o = ((size_t)b * LIN + (valid ? s : 0)) * CIN + c0 + lg * 8;
            const half8* ph = (const half8*)(xth + o);
            const half8* pl = (const half8*)(xtl + o);
            #pragma unroll
            for (int kc = 0; kc < 4; ++kc) {
                half8 vh = {}, vl = {};
                if (valid) { vh = ph[kc * 4]; vl = pl[kc * 4]; }
                ah[g][kc] = vh; al[g][kc] = vl;
            }
        }
        if (t < 8) stage(t + 1, buf ^ 1);
        const char* bhp = smem + buf * 65536;
        const char* blp = bhp + 32768;
        #pragma unroll 2
        for (int cg = 0; cg < 4; ++cg) {
            int col   = wc * 64 + cg * 16 + lr;
            int kswz  = (col & 7) << 4;
            int cbyte = col * 256;
            half8 bhf[4], blf[4];
            #pragma unroll
            for (int kc = 0; kc < 4; ++kc) {
                int kb = (kc * 64 + lg * 16) ^ kswz;
                bhf[kc] = *(const half8*)(bhp + cbyte + kb);
                blf[kc] = *(const half8*)(blp + cbyte + kb);
            }
            #pragma unroll
            for (int kc = 0; kc < 4; ++kc) {
                #pragma unroll
                for (int g = 0; g < 2; ++g) {
                    acc[g][cg] = __builtin_amdgcn_mfma_f32_16x16x32_f16(ah[g][kc], bhf[kc], acc[g][cg], 0, 0, 0);
                    acc[g][cg] = __builtin_amdgcn_mfma_f32_16x16x32_f16(al[g][kc], bhf[kc], acc[g][cg], 0, 0, 0);
                    acc[g][cg] = __builtin_amdgcn_mfma_f32_16x16x32_f16(ah[g][kc], blf[kc], acc[g][cg], 0, 0, 0);
                }
            }
        }
        __syncthreads();
        buf ^= 1;
    }

    float* pb = part + (size_t)ks * NROWS * DCODE;
    #pragma unroll
    for (int g = 0; g < 2; ++g)
        #pragma unroll
        for (int cg = 0; cg < 4; ++cg) {
            int col = wc * 64 + cg * 16 + lr;
            #pragma unroll
            for (int rr = 0; rr < 4; ++rr) {
                int row = r0 + wr * 32 + g * 16 + lg * 4 + rr;
                pb[(size_t)row * DCODE + col] = acc[g][cg][rr];
            }
        }
}

// ---------------------------------------------------------------------------
// Combine K-halves + L2-normalize encodings -> fp16 hi/lo split.
__global__ __launch_bounds__(256) void k_encnorm(const float* __restrict__ part,
                                                 half_t* __restrict__ eh,
                                                 half_t* __restrict__ el) {
    int wid  = threadIdx.x >> 6;
    int lane = threadIdx.x & 63;
    int r = blockIdx.x * 4 + wid;
    const float2* p0 = (const float2*)part + (size_t)r * 64;
    const float2* p1 = (const float2*)(part + (size_t)NROWS * DCODE) + (size_t)r * 64;
    float2 a = p0[lane];
    float2 c = p1[lane];
    a.x += c.x; a.y += c.y;
    float ss = a.x * a.x + a.y * a.y;
    #pragma unroll
    for (int m = 1; m < 64; m <<= 1) ss += __shfl_xor(ss, m);
    float inv = 1.0f / fmaxf(sqrtf(ss), EPS);
    float nx = a.x * inv, ny = a.y * inv;
    half_t hx = (half_t)nx, hy = (half_t)ny;
    half_t lx = (half_t)(nx - (float)hx), ly = (half_t)(ny - (float)hy);
    ((half2v*)eh)[(size_t)r * 64 + lane] = half2v{hx, hy};
    ((half2v*)el)[(size_t)r * 64 + lane] = half2v{lx, ly};
}

// ---------------------------------------------------------------------------
// MFMA dist+argmax (validated round 4). Block = 4 waves x 32 rows = 128 rows;
// blockIdx.y = col quarter. dot = hh + hl + lh (fp32-class).
__global__ __launch_bounds__(256, 1) void k_dist(const half_t* __restrict__ eh,
                                                 const half_t* __restrict__ el,
                                                 const half_t* __restrict__ ch,
                                                 const half_t* __restrict__ cl,
                                                 const float* __restrict__ cn2,
                                                 float* __restrict__ best_s,
                                                 int* __restrict__ best_i) {
    extern __shared__ char smem[];          // 2 x (32KB hi + 32KB lo)
    const int tid  = threadIdx.x;
    const int lane = tid & 63;
    const int w    = tid >> 6;
    const int lr   = lane & 15;
    const int lg   = lane >> 4;
    const int r0   = blockIdx.x * 128;
    const int kqbase = blockIdx.y * 2048;

    half8 ah[2][4], al[2][4];
    #pragma unroll
    for (int g = 0; g < 2; ++g) {
        int row = r0 + w * 32 + g * 16 + lr;
        const half8* ph = (const half8*)(eh + (size_t)row * 128 + lg * 8);
        const half8* pl = (const half8*)(el + (size_t)row * 128 + lg * 8);
        #pragma unroll
        for (int kc = 0; kc < 4; ++kc) { ah[g][kc] = ph[kc * 4]; al[g][kc] = pl[kc * 4]; }
    }

    const half_t* msrc = (w >> 1) ? cl : ch;
    auto stage = [&](int t, int buf) {
        #pragma unroll
        for (int i = 0; i < 16; ++i) {
            int col_l = (w & 1) * 64 + i * 4 + lg;
            int ksrc  = (lr * 16) ^ ((col_l & 7) << 4);
            const char* g = (const char*)msrc
                          + ((size_t)(kqbase + t * 128 + col_l)) * 256 + ksrc;
            char* l = smem + buf * 65536 + w * 16384 + i * 1024;
            __builtin_amdgcn_global_load_lds(
                (const __attribute__((address_space(1))) void*)(uintptr_t)g,
                (__attribute__((address_space(3))) void*)(uintptr_t)l, 16, 0, 0);
        }
    };

    float bs[2][4]; int bi[2][4];
    #pragma unroll
    for (int g = 0; g < 2; ++g)
        #pragma unroll
        for (int r = 0; r < 4; ++r) { bs[g][r] = -3.4e38f; bi[g][r] = 0; }

    stage(0, 0);
    __syncthreads();

    int buf = 0;
    for (int t = 0; t < 16; ++t) {
        if (t < 15) stage(t + 1, buf ^ 1);
        float cnv[8];
        #pragma unroll
        for (int cg = 0; cg < 8; ++cg)
            cnv[cg] = cn2[kqbase + t * 128 + cg * 16 + lr];
        const char* bhp = smem + buf * 65536;
        const char* blp = bhp + 32768;
        #pragma unroll 2
        for (int cg = 0; cg < 8; ++cg) {
            int col   = cg * 16 + lr;
            int kswz  = (col & 7) << 4;
            int cbyte = col * 256;
            half8 bhf[4], blf[4];
            #pragma unroll
            for (int kc = 0; kc < 4; ++kc) {
                int kb = (kc * 64 + lg * 16) ^ kswz;
                bhf[kc] = *(const half8*)(bhp + cbyte + kb);
                blf[kc] = *(const half8*)(blp + cbyte + kb);
            }
            f32x4 acc[2] = {f32x4{0.f,0.f,0.f,0.f}, f32x4{0.f,0.f,0.f,0.f}};
            #pragma unroll
            for (int kc = 0; kc < 4; ++kc) {
                #pragma unroll
                for (int g = 0; g < 2; ++g) {
                    acc[g] = __builtin_amdgcn_mfma_f32_16x16x32_f16(ah[g][kc], bhf[kc], acc[g], 0, 0, 0);
                    acc[g] = __builtin_amdgcn_mfma_f32_16x16x32_f16(al[g][kc], bhf[kc], acc[g], 0, 0, 0);
                    acc[g] = __builtin_amdgcn_mfma_f32_16x16x32_f16(ah[g][kc], blf[kc], acc[g], 0, 0, 0);
                }
            }
            int n = kqbase + t * 128 + cg * 16 + lr;
            #pragma unroll
            for (int g = 0; g < 2; ++g)
                #pragma unroll
                for (int r = 0; r < 4; ++r) {
                    float sc = 2.0f * acc[g][r] - cnv[cg];
                    if (sc > bs[g][r]) { bs[g][r] = sc; bi[g][r] = n; }
                }
        }
        __syncthreads();
        buf ^= 1;
    }

    #pragma unroll
    for (int g = 0; g < 2; ++g)
        #pragma unroll
        for (int r = 0; r < 4; ++r) {
            float s = bs[g][r]; int i = bi[g][r];
            #pragma unroll
            for (int m = 1; m < 16; m <<= 1) {
                float os = __shfl_xor(s, m);
                int   oi = __shfl_xor(i, m);
                if (os > s || (os == s && oi < i)) { s = os; i = oi; }
            }
            if (lr == 0) {
                int row = r0 + w * 32 + g * 16 + lg * 4 + r;
                best_s[(size_t)blockIdx.y * NROWS + row] = s;
                best_i[(size_t)blockIdx.y * NROWS + row] = i;
            }
        }
}

// ---------------------------------------------------------------------------
__global__ __launch_bounds__(256) void k_merge(const float* __restrict__ bs,
                                               const int* __restrict__ bi,
                                               int* __restrict__ out) {
    int r = blockIdx.x * 256 + threadIdx.x;
    if (r >= NROWS) return;
    float s = bs[r]; int i = bi[r];
    #pragma unroll
    for (int q = 1; q < 4; ++q) {
        float s2 = bs[(size_t)q * NROWS + r];
        int   i2 = bi[(size_t)q * NROWS + r];
        if (s2 > s || (s2 == s && i2 < i)) { s = s2; i = i2; }
    }
    out[r] = i;
}

// ---------------------------------------------------------------------------
extern "C" void kernel_launch(void* const* d_in, const int* in_sizes, int n_in,
                              void* d_out, int out_size, void* d_ws, size_t ws_size,
                              hipStream_t stream) {
    const float* x  = (const float*)d_in[0];
    const float* w  = (const float*)d_in[1];
    const float* cb = (const float*)d_in[2];
    char* ws = (char*)d_ws;
    float*  cn2  = (float*)(ws + OFF_CN2);
    float*  bs   = (float*)(ws + OFF_BS);
    int*    bi   = (int*)(ws + OFF_BI);
    half_t* eh   = (half_t*)(ws + OFF_EH);
    half_t* el   = (half_t*)(ws + OFF_EL);
    half_t* chh  = (half_t*)(ws + OFF_CH);
    half_t* cll  = (half_t*)(ws + OFF_CL);
    half_t* wht  = (half_t*)(ws + OFF_WHT);
    half_t* wlt  = (half_t*)(ws + OFF_WLT);
    float*  part = (float*)(ws + OFF_PART);
    half_t* xth  = (half_t*)(ws + OFF_XTH);
    half_t* xtl  = (half_t*)(ws + OFF_XTL);
    int*    out  = (int*)d_out;

    hipFuncSetAttribute((const void*)k_dist,
                        hipFuncAttributeMaxDynamicSharedMemorySize, 131072);
    hipFuncSetAttribute((const void*)k_conv_mfma,
                        hipFuncAttributeMaxDynamicSharedMemorySize, 131072);

    k_wt2     <<<dim3(9, 128), 256, 0, stream>>>(w, wht, wlt);
    k_cbnorm  <<<2048, 256, 0, stream>>>(cb, chh, cll, cn2);
    k_xt      <<<dim3(128, 24, 4), 256, 0, stream>>>(x, xth, xtl);
    k_conv_mfma<<<dim3(128, 2), 256, 131072, stream>>>(xth, xtl, wht, wlt, part);
    k_encnorm <<<2048, 256, 0, stream>>>(part, eh, el);
    k_dist    <<<dim3(64, 4), 256, 131072, stream>>>(eh, el, chh, cll, cn2, bs, bi);
    k_merge   <<<32, 256, 0, stream>>>(bs, bi, out);
}

// Round 6
// 204.210 us; speedup vs baseline: 2.9751x; 1.0133x over previous
//
#include <hip/hip_runtime.h>

#define EPS 1e-12f

// problem sizes
#define BATCH 4
#define CIN   768
#define LIN   4096
#define DCODE 128
#define TOUT  2048
#define NROWS (BATCH*TOUT)   // 8192
#define KCB   8192
#define KCONV 2304           // 3*768, k = j*768 + c (j-major)

// ws layout (bytes) — total ~68.6 MB
#define OFF_CN2  0u          // 8192 f32
#define OFF_BS   32768u      // 2*8192 f32
#define OFF_BI   163840u     // 2*8192 i32
#define OFF_EH   294912u     // 8192*128 f16
#define OFF_EL   2392064u
#define OFF_CH   4489216u
#define OFF_CL   6586368u
#define OFF_WHT  8683520u    // 128*2304 f16 = 589,824
#define OFF_WLT  9273344u
#define OFF_PART 9863168u    // 2*8192*128 f32 = 8,388,608
#define OFF_XTH  18251776u   // 4*4096*768 f16 = 25,165,824
#define OFF_XTL  43417600u   // end 68,583,424

typedef _Float16 half_t;
typedef __attribute__((ext_vector_type(8))) _Float16 half8;
typedef __attribute__((ext_vector_type(2))) _Float16 half2v;
typedef __attribute__((ext_vector_type(4))) float f32x4;

// ---------------------------------------------------------------------------
// Weights -> fp16 hi/lo, layout wT[n][k], k = j*768 + c.
__global__ __launch_bounds__(256) void k_wt2(const float* __restrict__ w,
                                             half_t* __restrict__ wht,
                                             half_t* __restrict__ wlt) {
    int k = blockIdx.x * 256 + threadIdx.x;
    int n = blockIdx.y;
    if (k >= KCONV) return;
    int j = (k >= 1536) ? 2 : (k >= 768) ? 1 : 0;
    int c = k - j * 768;
    float v = w[(size_t)n * KCONV + c * 3 + j];
    half_t h = (half_t)v;
    wht[(size_t)n * KCONV + k] = h;
    wlt[(size_t)n * KCONV + k] = (half_t)(v - (float)h);
}

// ---------------------------------------------------------------------------
// Transpose x[b][c][s] -> xt[b][s][c] as fp16 hi/lo (LDS 32x33 tile).
__global__ __launch_bounds__(256) void k_xt(const float* __restrict__ x,
                                            half_t* __restrict__ xth,
                                            half_t* __restrict__ xtl) {
    __shared__ float tile[32][33];
    const int s0 = blockIdx.x * 32;
    const int c0 = blockIdx.y * 32;
    const int b  = blockIdx.z;
    const int sl = threadIdx.x & 31;
    const int cl = threadIdx.x >> 5;
    const float* xg = x + ((size_t)b * CIN + c0) * LIN + s0;
    #pragma unroll
    for (int p = 0; p < 4; ++p) {
        int c = cl + p * 8;
        tile[c][sl] = xg[(size_t)c * LIN + sl];
    }
    __syncthreads();
    const int wcc = (threadIdx.x & 15) * 2;
    const int wss = threadIdx.x >> 4;
    #pragma unroll
    for (int p = 0; p < 2; ++p) {
        int s = wss + p * 16;
        float v0 = tile[wcc][s], v1 = tile[wcc + 1][s];
        half_t h0 = (half_t)v0, h1 = (half_t)v1;
        half_t l0 = (half_t)(v0 - (float)h0), l1 = (half_t)(v1 - (float)h1);
        size_t o = ((size_t)b * LIN + s0 + s) * CIN + c0 + wcc;
        *(half2v*)(xth + o) = half2v{h0, h1};
        *(half2v*)(xtl + o) = half2v{l0, l1};
    }
}

// ---------------------------------------------------------------------------
// Normalize codebook rows -> fp16 hi/lo split; cn2[k] = ||c_norm||^2.
__global__ __launch_bounds__(256) void k_cbnorm(const float* __restrict__ cb,
                                                half_t* __restrict__ ch,
                                                half_t* __restrict__ cl,
                                                float* __restrict__ cn2) {
    int wid  = threadIdx.x >> 6;
    int lane = threadIdx.x & 63;
    int k = blockIdx.x * 4 + wid;
    const float2* src = (const float2*)cb + (size_t)k * 64;
    float2 v = src[lane];
    float ss = v.x * v.x + v.y * v.y;
    #pragma unroll
    for (int m = 1; m < 64; m <<= 1) ss += __shfl_xor(ss, m);
    float inv = 1.0f / fmaxf(sqrtf(ss), EPS);
    float nx = v.x * inv, ny = v.y * inv;
    half_t hx = (half_t)nx, hy = (half_t)ny;
    half_t lx = (half_t)(nx - (float)hx), ly = (half_t)(ny - (float)hy);
    ((half2v*)ch)[(size_t)k * 64 + lane] = half2v{hx, hy};
    ((half2v*)cl)[(size_t)k * 64 + lane] = half2v{lx, ly};
    if (lane == 0) cn2[k] = ss * inv * inv;
}

// ---------------------------------------------------------------------------
// Conv as MFMA GEMM (round-5: kc-outer, B-frags hoisted -> 8 indep acc chains).
__global__ __launch_bounds__(256, 1) void k_conv_mfma(
        const half_t* __restrict__ xth, const half_t* __restrict__ xtl,
        const half_t* __restrict__ wht, const half_t* __restrict__ wlt,
        float* __restrict__ part) {
    extern __shared__ char smem[];   // 2 x (32KB hi + 32KB lo)
    const int tid  = threadIdx.x;
    const int lane = tid & 63;
    const int w    = tid >> 6;
    const int wr   = w >> 1;
    const int wc   = w & 1;
    const int lr   = lane & 15;
    const int lg   = lane >> 4;
    const int r0   = blockIdx.x * 64;
    const int ks   = blockIdx.y;
    const int b    = r0 >> 11;
    const int t00  = r0 & 2047;
    const int kbase = ks * 1152;

    const half_t* msrc = (w >> 1) ? wlt : wht;
    auto stage = [&](int t, int buf) {
        int k0 = kbase + t * 128;
        #pragma unroll
        for (int i = 0; i < 16; ++i) {
            int col_l = (w & 1) * 64 + i * 4 + lg;
            int ksrc  = (lr * 16) ^ ((col_l & 7) << 4);   // inverse swizzle
            const char* g = (const char*)msrc + (size_t)col_l * 4608
                          + (size_t)k0 * 2 + ksrc;
            char* l = smem + buf * 65536 + w * 16384 + i * 1024;  // +lane*16 HW
            __builtin_amdgcn_global_load_lds(
                (const __attribute__((address_space(1))) void*)(uintptr_t)g,
                (__attribute__((address_space(3))) void*)(uintptr_t)l, 16, 0, 0);
        }
    };

    f32x4 acc[2][4];
    #pragma unroll
    for (int g = 0; g < 2; ++g)
        #pragma unroll
        for (int cg = 0; cg < 4; ++cg) acc[g][cg] = f32x4{0.f, 0.f, 0.f, 0.f};

    stage(0, 0);
    __syncthreads();

    int buf = 0;
    for (int t = 0; t < 9; ++t) {
        int k0 = kbase + t * 128;
        int j  = (k0 >= 1536) ? 2 : (k0 >= 768) ? 1 : 0;
        int c0 = k0 - j * 768;
        half8 ah[2][4], al[2][4];
        #pragma unroll
        for (int g = 0; g < 2; ++g) {
            int trow = t00 + wr * 32 + g * 16 + lr;
            int s = 2 * trow - 1 + j;
            bool valid = (unsigned)s < (unsigned)LIN;
            size_t o = ((size_t)b * LIN + (valid ? s : 0)) * CIN + c0 + lg * 8;
            const half8* ph = (const half8*)(xth + o);
            const half8* pl = (const half8*)(xtl + o);
            #pragma unroll
            for (int kc = 0; kc < 4; ++kc) {
                half8 vh = {}, vl = {};
                if (valid) { vh = ph[kc * 4]; vl = pl[kc * 4]; }
                ah[g][kc] = vh; al[g][kc] = vl;
            }
        }
        if (t < 8) stage(t + 1, buf ^ 1);
        const char* bhp = smem + buf * 65536;
        const char* blp = bhp + 32768;
        #pragma unroll
        for (int kc = 0; kc < 4; ++kc) {
            half8 bhf[4], blf[4];
            #pragma unroll
            for (int cg = 0; cg < 4; ++cg) {
                int col   = wc * 64 + cg * 16 + lr;
                int kswz  = (col & 7) << 4;
                int cbyte = col * 256;
                int kb    = (kc * 64 + lg * 16) ^ kswz;
                bhf[cg] = *(const half8*)(bhp + cbyte + kb);
                blf[cg] = *(const half8*)(blp + cbyte + kb);
            }
            #pragma unroll
            for (int cg = 0; cg < 4; ++cg)
                #pragma unroll
                for (int g = 0; g < 2; ++g)
                    acc[g][cg] = __builtin_amdgcn_mfma_f32_16x16x32_f16(ah[g][kc], bhf[cg], acc[g][cg], 0, 0, 0);
            #pragma unroll
            for (int cg = 0; cg < 4; ++cg)
                #pragma unroll
                for (int g = 0; g < 2; ++g)
                    acc[g][cg] = __builtin_amdgcn_mfma_f32_16x16x32_f16(al[g][kc], bhf[cg], acc[g][cg], 0, 0, 0);
            #pragma unroll
            for (int cg = 0; cg < 4; ++cg)
                #pragma unroll
                for (int g = 0; g < 2; ++g)
                    acc[g][cg] = __builtin_amdgcn_mfma_f32_16x16x32_f16(ah[g][kc], blf[cg], acc[g][cg], 0, 0, 0);
        }
        __syncthreads();
        buf ^= 1;
    }

    float* pb = part + (size_t)ks * NROWS * DCODE;
    #pragma unroll
    for (int g = 0; g < 2; ++g)
        #pragma unroll
        for (int cg = 0; cg < 4; ++cg) {
            int col = wc * 64 + cg * 16 + lr;
            #pragma unroll
            for (int rr = 0; rr < 4; ++rr) {
                int row = r0 + wr * 32 + g * 16 + lg * 4 + rr;
                pb[(size_t)row * DCODE + col] = acc[g][cg][rr];
            }
        }
}

// ---------------------------------------------------------------------------
// Combine K-halves + L2-normalize encodings -> fp16 hi/lo split.
__global__ __launch_bounds__(256) void k_encnorm(const float* __restrict__ part,
                                                 half_t* __restrict__ eh,
                                                 half_t* __restrict__ el) {
    int wid  = threadIdx.x >> 6;
    int lane = threadIdx.x & 63;
    int r = blockIdx.x * 4 + wid;
    const float2* p0 = (const float2*)part + (size_t)r * 64;
    const float2* p1 = (const float2*)(part + (size_t)NROWS * DCODE) + (size_t)r * 64;
    float2 a = p0[lane];
    float2 c = p1[lane];
    a.x += c.x; a.y += c.y;
    float ss = a.x * a.x + a.y * a.y;
    #pragma unroll
    for (int m = 1; m < 64; m <<= 1) ss += __shfl_xor(ss, m);
    float inv = 1.0f / fmaxf(sqrtf(ss), EPS);
    float nx = a.x * inv, ny = a.y * inv;
    half_t hx = (half_t)nx, hy = (half_t)ny;
    half_t lx = (half_t)(nx - (float)hx), ly = (half_t)(ny - (float)hy);
    ((half2v*)eh)[(size_t)r * 64 + lane] = half2v{hx, hy};
    ((half2v*)el)[(size_t)r * 64 + lane] = half2v{lx, ly};
}

// ---------------------------------------------------------------------------
// MFMA dist+argmax, round-5 col-split: block = 64 rows, waves split the
// 128-col tile (32 cols/wave); A (all 64 rows) in regs, identical for all
// waves. blockIdx.y = col HALF (4096 codewords, 32 tiles). Staging and all
// fragment maps identical to the round-4 validated kernel.
__global__ __launch_bounds__(256, 1) void k_dist(const half_t* __restrict__ eh,
                                                 const half_t* __restrict__ el,
                                                 const half_t* __restrict__ ch,
                                                 const half_t* __restrict__ cl,
                                                 const float* __restrict__ cn2,
                                                 float* __restrict__ best_s,
                                                 int* __restrict__ best_i) {
    extern __shared__ char smem[];          // 2 x (32KB hi + 32KB lo)
    const int tid  = threadIdx.x;
    const int lane = tid & 63;
    const int w    = tid >> 6;
    const int lr   = lane & 15;
    const int lg   = lane >> 4;
    const int r0   = blockIdx.x * 64;
    const int kqbase = blockIdx.y * 4096;

    // A: rows r0 + g*16 + lr (same for every wave), k = kc*32 + lg*8
    half8 ah[4][4], al[4][4];
    #pragma unroll
    for (int g = 0; g < 4; ++g) {
        int row = r0 + g * 16 + lr;
        const half8* ph = (const half8*)(eh + (size_t)row * 128 + lg * 8);
        const half8* pl = (const half8*)(el + (size_t)row * 128 + lg * 8);
        #pragma unroll
        for (int kc = 0; kc < 4; ++kc) { ah[g][kc] = ph[kc * 4]; al[g][kc] = pl[kc * 4]; }
    }

    const half_t* msrc = (w >> 1) ? cl : ch;
    auto stage = [&](int t, int buf) {
        #pragma unroll
        for (int i = 0; i < 16; ++i) {
            int col_l = (w & 1) * 64 + i * 4 + lg;
            int ksrc  = (lr * 16) ^ ((col_l & 7) << 4);
            const char* g = (const char*)msrc
                          + ((size_t)(kqbase + t * 128 + col_l)) * 256 + ksrc;
            char* l = smem + buf * 65536 + w * 16384 + i * 1024;
            __builtin_amdgcn_global_load_lds(
                (const __attribute__((address_space(1))) void*)(uintptr_t)g,
                (__attribute__((address_space(3))) void*)(uintptr_t)l, 16, 0, 0);
        }
    };

    float bs[4][4]; int bi[4][4];
    #pragma unroll
    for (int g = 0; g < 4; ++g)
        #pragma unroll
        for (int rr = 0; rr < 4; ++rr) { bs[g][rr] = -3.4e38f; bi[g][rr] = 0; }

    stage(0, 0);
    __syncthreads();

    int buf = 0;
    for (int t = 0; t < 32; ++t) {
        if (t < 31) stage(t + 1, buf ^ 1);
        float cnv[2];
        #pragma unroll
        for (int cg = 0; cg < 2; ++cg)
            cnv[cg] = cn2[kqbase + t * 128 + w * 32 + cg * 16 + lr];
        const char* bhp = smem + buf * 65536;
        const char* blp = bhp + 32768;
        f32x4 acc[4][2];
        #pragma unroll
        for (int g = 0; g < 4; ++g)
            #pragma unroll
            for (int cg = 0; cg < 2; ++cg) acc[g][cg] = f32x4{0.f, 0.f, 0.f, 0.f};
        #pragma unroll
        for (int kc = 0; kc < 4; ++kc) {
            half8 bhf[2], blf[2];
            #pragma unroll
            for (int cg = 0; cg < 2; ++cg) {
                int col   = w * 32 + cg * 16 + lr;
                int kswz  = (col & 7) << 4;
                int cbyte = col * 256;
                int kb    = (kc * 64 + lg * 16) ^ kswz;
                bhf[cg] = *(const half8*)(bhp + cbyte + kb);
                blf[cg] = *(const half8*)(blp + cbyte + kb);
            }
            #pragma unroll
            for (int cg = 0; cg < 2; ++cg)
                #pragma unroll
                for (int g = 0; g < 4; ++g)
                    acc[g][cg] = __builtin_amdgcn_mfma_f32_16x16x32_f16(ah[g][kc], bhf[cg], acc[g][cg], 0, 0, 0);
            #pragma unroll
            for (int cg = 0; cg < 2; ++cg)
                #pragma unroll
                for (int g = 0; g < 4; ++g)
                    acc[g][cg] = __builtin_amdgcn_mfma_f32_16x16x32_f16(al[g][kc], bhf[cg], acc[g][cg], 0, 0, 0);
            #pragma unroll
            for (int cg = 0; cg < 2; ++cg)
                #pragma unroll
                for (int g = 0; g < 4; ++g)
                    acc[g][cg] = __builtin_amdgcn_mfma_f32_16x16x32_f16(ah[g][kc], blf[cg], acc[g][cg], 0, 0, 0);
        }
        #pragma unroll
        for (int g = 0; g < 4; ++g)
            #pragma unroll
            for (int cg = 0; cg < 2; ++cg) {
                int n = kqbase + t * 128 + w * 32 + cg * 16 + lr;
                #pragma unroll
                for (int rr = 0; rr < 4; ++rr) {
                    float sc = 2.0f * acc[g][cg][rr] - cnv[cg];
                    if (sc > bs[g][rr]) { bs[g][rr] = sc; bi[g][rr] = n; }
                }
            }
        __syncthreads();
        buf ^= 1;
    }

    // reduce over the 16 lr lanes (cols within wave), then across waves in LDS
    float* redS = (float*)smem;          // [4][64]
    int*   redI = (int*)(smem + 1024);   // [4][64]
    #pragma unroll
    for (int g = 0; g < 4; ++g)
        #pragma unroll
        for (int rr = 0; rr < 4; ++rr) {
            float s = bs[g][rr]; int i = bi[g][rr];
            #pragma unroll
            for (int m = 1; m < 16; m <<= 1) {
                float os = __shfl_xor(s, m);
                int   oi = __shfl_xor(i, m);
                if (os > s || (os == s && oi < i)) { s = os; i = oi; }
            }
            if (lr == 0) {
                int row = g * 16 + lg * 4 + rr;
                redS[w * 64 + row] = s;
                redI[w * 64 + row] = i;
            }
        }
    __syncthreads();
    if (tid < 64) {
        float s = redS[tid]; int i = redI[tid];
        #pragma unroll
        for (int w2 = 1; w2 < 4; ++w2) {
            float s2 = redS[w2 * 64 + tid];
            int   i2 = redI[w2 * 64 + tid];
            if (s2 > s || (s2 == s && i2 < i)) { s = s2; i = i2; }
        }
        best_s[(size_t)blockIdx.y * NROWS + r0 + tid] = s;
        best_i[(size_t)blockIdx.y * NROWS + r0 + tid] = i;
    }
}

// ---------------------------------------------------------------------------
__global__ __launch_bounds__(256) void k_merge(const float* __restrict__ bs,
                                               const int* __restrict__ bi,
                                               int* __restrict__ out) {
    int r = blockIdx.x * 256 + threadIdx.x;
    if (r >= NROWS) return;
    float s = bs[r]; int i = bi[r];
    #pragma unroll
    for (int q = 1; q < 2; ++q) {
        float s2 = bs[(size_t)q * NROWS + r];
        int   i2 = bi[(size_t)q * NROWS + r];
        if (s2 > s || (s2 == s && i2 < i)) { s = s2; i = i2; }
    }
    out[r] = i;
}

// ---------------------------------------------------------------------------
extern "C" void kernel_launch(void* const* d_in, const int* in_sizes, int n_in,
                              void* d_out, int out_size, void* d_ws, size_t ws_size,
                              hipStream_t stream) {
    const float* x  = (const float*)d_in[0];
    const float* w  = (const float*)d_in[1];
    const float* cb = (const float*)d_in[2];
    char* ws = (char*)d_ws;
    float*  cn2  = (float*)(ws + OFF_CN2);
    float*  bs   = (float*)(ws + OFF_BS);
    int*    bi   = (int*)(ws + OFF_BI);
    half_t* eh   = (half_t*)(ws + OFF_EH);
    half_t* el   = (half_t*)(ws + OFF_EL);
    half_t* chh  = (half_t*)(ws + OFF_CH);
    half_t* cll  = (half_t*)(ws + OFF_CL);
    half_t* wht  = (half_t*)(ws + OFF_WHT);
    half_t* wlt  = (half_t*)(ws + OFF_WLT);
    float*  part = (float*)(ws + OFF_PART);
    half_t* xth  = (half_t*)(ws + OFF_XTH);
    half_t* xtl  = (half_t*)(ws + OFF_XTL);
    int*    out  = (int*)d_out;

    hipFuncSetAttribute((const void*)k_dist,
                        hipFuncAttributeMaxDynamicSharedMemorySize, 131072);
    hipFuncSetAttribute((const void*)k_conv_mfma,
                        hipFuncAttributeMaxDynamicSharedMemorySize, 131072);

    k_wt2     <<<dim3(9, 128), 256, 0, stream>>>(w, wht, wlt);
    k_cbnorm  <<<2048, 256, 0, stream>>>(cb, chh, cll, cn2);
    k_xt      <<<dim3(128, 24, 4), 256, 0, stream>>>(x, xth, xtl);
    k_conv_mfma<<<dim3(128, 2), 256, 131072, stream>>>(xth, xtl, wht, wlt, part);
    k_encnorm <<<2048, 256, 0, stream>>>(part, eh, el);
    k_dist    <<<dim3(128, 2), 256, 131072, stream>>>(eh, el, chh, cll, cn2, bs, bi);
    k_merge   <<<32, 256, 0, stream>>>(bs, bi, out);
}